// Round 1
// baseline (561.840 us; speedup 1.0000x reference)
//
#include <hip/hip_runtime.h>
#include <hip/hip_bf16.h>

// SoftSOM: dists = cdist(x, P); W = softmax(-dists/0.4); blended = W @ P
// N=524288 tokens, D=128, M=256 protos. Outputs: blended [N,128] f32, weights [N,256] f32.

#define N_TOK 524288
#define DIM 128
#define M_PROTO 256

typedef __attribute__((ext_vector_type(8))) short bf16x8;
typedef __attribute__((ext_vector_type(4))) float f32x4;
typedef __attribute__((ext_vector_type(4))) unsigned short us4;

static __device__ __forceinline__ unsigned short f2bf(float f) {
    unsigned int u = __float_as_uint(f);
    u += 0x7FFFu + ((u >> 16) & 1u);   // round-to-nearest-even
    return (unsigned short)(u >> 16);
}
static __device__ __forceinline__ float bf2f(unsigned short h) {
    return __uint_as_float(((unsigned int)h) << 16);
}

// ---------------------------------------------------------------------------
// Prep: split P into bf16 hi/lo, pre-laid-out in MFMA fragment order.
//  - Cross  (S^T = P @ X^T): A-frag = P[proto][k].  lane l holds
//      A[row = l&15][k = 8*(l>>4)+j], frags indexed [kt(4)][mfrag(16)].
//  - Blended (Bl = W @ P):   B-frag = P[k=proto][n=d]. lane l holds
//      B[k = 8*(l>>4)+j][col = l&15], frags indexed [kt2(8)][ng(8)].
// Also p_sq[256].
// ---------------------------------------------------------------------------
__global__ void __launch_bounds__(128) prep_kernel(
        const float* __restrict__ P,
        unsigned short* __restrict__ PfH, unsigned short* __restrict__ PfL,
        unsigned short* __restrict__ PTfH, unsigned short* __restrict__ PTfL,
        float* __restrict__ psq) {
    int m = blockIdx.x;      // proto 0..255
    int d = threadIdx.x;     // dim   0..127
    float v = P[m * DIM + d];
    unsigned short hi = f2bf(v);
    unsigned short lo = f2bf(v - bf2f(hi));

    // cross A-frag position (A = P, rows=proto, k=d)
    int ci = (((d >> 5) * 16 + (m >> 4)) * 64 + (((d >> 3) & 3) * 16 + (m & 15))) * 8 + (d & 7);
    PfH[ci] = hi; PfL[ci] = lo;

    // blended B-frag position (B = P, k=m(proto), col=d)
    int bi = (((m >> 5) * 8 + (d >> 4)) * 64 + (((m >> 3) & 3) * 16 + (d & 15))) * 8 + (m & 7);
    PTfH[bi] = hi; PTfL[bi] = lo;

    // psq reduce over 128 threads (2 waves)
    float s = v * v;
    #pragma unroll
    for (int off = 1; off < 64; off <<= 1) s += __shfl_xor(s, off, 64);
    __shared__ float part[2];
    if ((threadIdx.x & 63) == 0) part[threadIdx.x >> 6] = s;
    __syncthreads();
    if (threadIdx.x == 0) psq[m] = part[0] + part[1];
}

// ---------------------------------------------------------------------------
// Main fused kernel: 64 tokens per block, 256 threads (4 waves, 16 tok/wave).
// Phase 1: stage X tile -> LDS as bf16 hi/lo (padded rows), compute x_sq.
// Phase 2: per wave, S^T[256 proto][16 tok] via mfma_f32_16x16x32_bf16,
//          hi/lo split (3 MFMA per frag).  Lane holds 64 logits of 1 token.
// Phase 3: in-register softmax (2 shfl_xor for cross-group reduce).
// Phase 4: W tile (bf16) -> LDS (reusing X space), coalesced f32 writes.
// Phase 5: blended = W @ P via MFMA (P hi/lo), direct f32 stores.
// ---------------------------------------------------------------------------
__global__ void __launch_bounds__(256) softsom_main(
        const float* __restrict__ X,
        const unsigned short* __restrict__ PfH, const unsigned short* __restrict__ PfL,
        const unsigned short* __restrict__ PTfH, const unsigned short* __restrict__ PTfL,
        const float* __restrict__ psq,
        float* __restrict__ blended, float* __restrict__ weights) {

    // X region: 2 * 64 * 136 ushort = 34816 B ; W region: 64 * 264 ushort = 33792 B
    __shared__ __align__(16) unsigned char smem[34816];
    unsigned short (*Xhi)[136] = (unsigned short (*)[136])smem;
    unsigned short (*Xlo)[136] = (unsigned short (*)[136])(smem + 17408);
    unsigned short (*Wl)[264]  = (unsigned short (*)[264])smem;   // aliases X (barrier-protected)
    __shared__ float s_xsq[64];
    __shared__ float s_psq[256];

    const int t = threadIdx.x;
    const long base_tok = (long)blockIdx.x * 64;

    s_psq[t] = psq[t];

    // ---- Phase 1: stage X (4 threads per row, 32 floats each) ----
    {
        int r  = t >> 2;
        int c0 = (t & 3) * 32;
        const float4* xr = (const float4*)(X + (base_tok + r) * DIM + c0);
        float ps = 0.f;
        #pragma unroll
        for (int i = 0; i < 8; ++i) {
            float4 v = xr[i];
            ps += v.x * v.x + v.y * v.y + v.z * v.z + v.w * v.w;
            unsigned short h0 = f2bf(v.x), h1 = f2bf(v.y), h2 = f2bf(v.z), h3 = f2bf(v.w);
            us4 hv = {h0, h1, h2, h3};
            us4 lv = {f2bf(v.x - bf2f(h0)), f2bf(v.y - bf2f(h1)),
                      f2bf(v.z - bf2f(h2)), f2bf(v.w - bf2f(h3))};
            *(us4*)&Xhi[r][c0 + i * 4] = hv;
            *(us4*)&Xlo[r][c0 + i * 4] = lv;
        }
        ps += __shfl_xor(ps, 1, 64);
        ps += __shfl_xor(ps, 2, 64);
        if ((t & 3) == 0) s_xsq[r] = ps;
    }
    __syncthreads();

    const int w = t >> 6;          // wave 0..3
    const int l = t & 63;          // lane
    const int c = l & 15;
    const int g = l >> 4;
    const int myrow = w * 16 + c;  // this lane's token row within the tile

    // ---- Phase 2: cross S^T = P @ X^T ----
    f32x4 acc[16];
    #pragma unroll
    for (int m = 0; m < 16; ++m) acc[m] = (f32x4){0.f, 0.f, 0.f, 0.f};

    const bf16x8* pfh = (const bf16x8*)PfH;
    const bf16x8* pfl = (const bf16x8*)PfL;

    #pragma unroll
    for (int kt = 0; kt < 4; ++kt) {
        bf16x8 bh = *(const bf16x8*)&Xhi[myrow][kt * 32 + g * 8];
        bf16x8 bl = *(const bf16x8*)&Xlo[myrow][kt * 32 + g * 8];
        #pragma unroll
        for (int m = 0; m < 16; ++m) {
            bf16x8 ah = pfh[(kt * 16 + m) * 64 + l];
            bf16x8 al = pfl[(kt * 16 + m) * 64 + l];
            acc[m] = __builtin_amdgcn_mfma_f32_16x16x32_bf16(ah, bh, acc[m], 0, 0, 0);
            acc[m] = __builtin_amdgcn_mfma_f32_16x16x32_bf16(al, bh, acc[m], 0, 0, 0);
            acc[m] = __builtin_amdgcn_mfma_f32_16x16x32_bf16(ah, bl, acc[m], 0, 0, 0);
        }
    }

    // ---- Phase 3: softmax over protos (lane-local 64 + 2 shfl_xor) ----
    const float xq = s_xsq[myrow];
    float mx = -3.4e38f;
    #pragma unroll
    for (int m = 0; m < 16; ++m) {
        #pragma unroll
        for (int r = 0; r < 4; ++r) {
            int proto = m * 16 + g * 4 + r;
            float s2 = fmaxf(xq + s_psq[proto] - 2.f * acc[m][r], 0.f);
            float lg = -sqrtf(s2) * 2.5f;   // 1/T = 1/0.4
            acc[m][r] = lg;
            mx = fmaxf(mx, lg);
        }
    }
    mx = fmaxf(mx, __shfl_xor(mx, 16, 64));
    mx = fmaxf(mx, __shfl_xor(mx, 32, 64));
    float sum = 0.f;
    #pragma unroll
    for (int m = 0; m < 16; ++m) {
        #pragma unroll
        for (int r = 0; r < 4; ++r) {
            float p = __expf(acc[m][r] - mx);
            acc[m][r] = p;
            sum += p;
        }
    }
    sum += __shfl_xor(sum, 16, 64);
    sum += __shfl_xor(sum, 32, 64);
    const float inv = 1.0f / sum;

    // ---- Phase 4: W -> LDS (bf16), then coalesced f32 weight writes ----
    __syncthreads();   // all waves done reading X before overwriting with Wl
    #pragma unroll
    for (int m = 0; m < 16; ++m) {
        us4 wv = {f2bf(acc[m][0] * inv), f2bf(acc[m][1] * inv),
                  f2bf(acc[m][2] * inv), f2bf(acc[m][3] * inv)};
        *(us4*)&Wl[myrow][m * 16 + g * 4] = wv;
    }
    __syncthreads();

    {
        float* wout = weights + base_tok * M_PROTO;
        #pragma unroll
        for (int i = 0; i < 16; ++i) {
            int idx = i * 256 + t;
            int row = idx >> 6;
            int c4  = (idx & 63) * 4;
            us4 wv = *(const us4*)&Wl[row][c4];
            float4 o = {bf2f(wv[0]), bf2f(wv[1]), bf2f(wv[2]), bf2f(wv[3])};
            *(float4*)&wout[row * M_PROTO + c4] = o;
        }
    }

    // ---- Phase 5: blended = W @ P  (K=256, wave handles 32 of 128 cols) ----
    f32x4 acc2[4][2];
    #pragma unroll
    for (int m = 0; m < 4; ++m)
        #pragma unroll
        for (int n = 0; n < 2; ++n) acc2[m][n] = (f32x4){0.f, 0.f, 0.f, 0.f};

    const bf16x8* pth = (const bf16x8*)PTfH;
    const bf16x8* ptl = (const bf16x8*)PTfL;

    #pragma unroll
    for (int kt = 0; kt < 8; ++kt) {
        bf16x8 aw[4];
        #pragma unroll
        for (int m = 0; m < 4; ++m)
            aw[m] = *(const bf16x8*)&Wl[m * 16 + c][kt * 32 + g * 8];
        #pragma unroll
        for (int n = 0; n < 2; ++n) {
            int ng = w * 2 + n;
            bf16x8 bh = pth[(kt * 8 + ng) * 64 + l];
            bf16x8 bl = ptl[(kt * 8 + ng) * 64 + l];
            #pragma unroll
            for (int m = 0; m < 4; ++m) {
                acc2[m][n] = __builtin_amdgcn_mfma_f32_16x16x32_bf16(aw[m], bh, acc2[m][n], 0, 0, 0);
                acc2[m][n] = __builtin_amdgcn_mfma_f32_16x16x32_bf16(aw[m], bl, acc2[m][n], 0, 0, 0);
            }
        }
    }

    float* bout = blended + base_tok * DIM;
    #pragma unroll
    for (int m = 0; m < 4; ++m)
        #pragma unroll
        for (int n = 0; n < 2; ++n)
            #pragma unroll
            for (int r = 0; r < 4; ++r) {
                int row = m * 16 + g * 4 + r;
                int d   = w * 32 + n * 16 + c;
                bout[row * DIM + d] = acc2[m][n][r];
            }
}

extern "C" void kernel_launch(void* const* d_in, const int* in_sizes, int n_in,
                              void* d_out, int out_size, void* d_ws, size_t ws_size,
                              hipStream_t stream) {
    const float* x = (const float*)d_in[0];
    const float* protos = (const float*)d_in[1];

    float* out = (float*)d_out;
    float* blended = out;                               // [N,128]
    float* weights = out + (size_t)N_TOK * DIM;         // [N,256]

    unsigned short* PfH  = (unsigned short*)d_ws;       // 32768 elems each
    unsigned short* PfL  = PfH  + 32768;
    unsigned short* PTfH = PfL  + 32768;
    unsigned short* PTfL = PTfH + 32768;
    float*          psq  = (float*)(PTfL + 32768);      // 256 f32

    prep_kernel<<<M_PROTO, DIM, 0, stream>>>(protos, PfH, PfL, PTfH, PTfL, psq);
    softsom_main<<<N_TOK / 64, 256, 0, stream>>>(x, PfH, PfL, PTfH, PTfL, psq,
                                                 blended, weights);
}

// Round 2
// 310.855 us; speedup vs baseline: 1.8074x; 1.8074x over previous
//
#include <hip/hip_runtime.h>
#include <hip/hip_bf16.h>

// SoftSOM: dists = cdist(x, P); W = softmax(-dists/0.4); blended = W @ P
// N=524288 tokens, D=128, M=256 protos. Outputs: blended [N,128] f32, weights [N,256] f32.

#define N_TOK 524288
#define DIM 128
#define M_PROTO 256

typedef __attribute__((ext_vector_type(8))) short bf16x8;
typedef __attribute__((ext_vector_type(4))) float f32x4;
typedef __attribute__((ext_vector_type(4))) unsigned short us4;

static __device__ __forceinline__ unsigned short f2bf(float f) {
    unsigned int u = __float_as_uint(f);
    u += 0x7FFFu + ((u >> 16) & 1u);   // round-to-nearest-even
    return (unsigned short)(u >> 16);
}
static __device__ __forceinline__ float bf2f(unsigned short h) {
    return __uint_as_float(((unsigned int)h) << 16);
}

// ---------------------------------------------------------------------------
// Prep: P -> bf16 fragments.
//  - Cross  (S^T = P @ X^T): A-frag, SINGLE bf16 (X carries hi/lo exactness).
//      PfH[(kt*16 + mfrag)*64 + lane]*8 + j ; kt=d>>5, mfrag=m>>4,
//      lane = ((d>>3)&3)*16 + (m&15), j = d&7.
//  - Blended (Bl = W @ P): B-frag, hi/lo split.
//      PT*[(kt2*8 + ng)*64 + lane]*8 + j ; kt2=m>>5, ng=d>>4,
//      lane = ((m>>3)&3)*16 + (d&15), j = m&7.
// Also p_sq[256].
// ---------------------------------------------------------------------------
__global__ void __launch_bounds__(128) prep_kernel(
        const float* __restrict__ P,
        unsigned short* __restrict__ PfH,
        unsigned short* __restrict__ PTfH, unsigned short* __restrict__ PTfL,
        float* __restrict__ psq) {
    int m = blockIdx.x;      // proto 0..255
    int d = threadIdx.x;     // dim   0..127
    float v = P[m * DIM + d];
    unsigned short hi = f2bf(v);
    unsigned short lo = f2bf(v - bf2f(hi));

    // cross A-frag position (A = P, rows=proto, k=d) — hi only
    int ci = (((d >> 5) * 16 + (m >> 4)) * 64 + (((d >> 3) & 3) * 16 + (m & 15))) * 8 + (d & 7);
    PfH[ci] = hi;

    // blended B-frag position (B = P, k=m(proto), col=d) — hi/lo
    int bi = (((m >> 5) * 8 + (d >> 4)) * 64 + (((m >> 3) & 3) * 16 + (d & 15))) * 8 + (m & 7);
    PTfH[bi] = hi; PTfL[bi] = lo;

    // psq reduce over 128 threads (2 waves)
    float s = v * v;
    #pragma unroll
    for (int off = 1; off < 64; off <<= 1) s += __shfl_xor(s, off, 64);
    __shared__ float part[2];
    if ((threadIdx.x & 63) == 0) part[threadIdx.x >> 6] = s;
    __syncthreads();
    if (threadIdx.x == 0) psq[m] = part[0] + part[1];
}

// ---------------------------------------------------------------------------
// Main fused kernel: 128 tokens per block, 512 threads (8 waves, 16 tok/wave).
// Phase 1: stage X tile -> LDS as bf16 hi/lo, compute x_sq.
// Phase 2: per wave, S^T[256 proto][16 tok] via mfma_f32_16x16x32_bf16;
//          P single-bf16, X hi/lo (2 MFMA per frag). Lane holds 64 logits
//          of 1 token.
// Phase 3: in-register softmax (2 shfl_xor for cross-group reduce).
// Phase 4: W tile (bf16) -> LDS (aliasing X), coalesced f32 weight writes.
// Phase 5: blended = W @ P via MFMA (P hi/lo), 64B-chunk f32 stores.
// ---------------------------------------------------------------------------
__global__ void __launch_bounds__(512, 4) softsom_main(
        const float* __restrict__ X,
        const unsigned short* __restrict__ PfH,
        const unsigned short* __restrict__ PTfH, const unsigned short* __restrict__ PTfL,
        const float* __restrict__ psq,
        float* __restrict__ blended, float* __restrict__ weights) {

    // X region: 2 * 128 * 136 ushort = 69632 B ; W region: 128 * 264 ushort = 67584 B
    __shared__ __align__(16) unsigned char smem[69632];
    unsigned short (*Xhi)[136] = (unsigned short (*)[136])smem;
    unsigned short (*Xlo)[136] = (unsigned short (*)[136])(smem + 34816);
    unsigned short (*Wl)[264]  = (unsigned short (*)[264])smem;   // aliases X (barrier-protected)
    __shared__ float s_xsq[128];
    __shared__ float s_psq[256];

    const int t = threadIdx.x;
    const long base_tok = (long)blockIdx.x * 128;

    if (t < 256) s_psq[t] = psq[t];

    // ---- Phase 1: stage X (4 threads per row, 32 floats each) ----
    {
        int r  = t >> 2;
        int c0 = (t & 3) * 32;
        const float4* xr = (const float4*)(X + (base_tok + r) * DIM + c0);
        float ps = 0.f;
        #pragma unroll
        for (int i = 0; i < 8; ++i) {
            float4 v = xr[i];
            ps += v.x * v.x + v.y * v.y + v.z * v.z + v.w * v.w;
            unsigned short h0 = f2bf(v.x), h1 = f2bf(v.y), h2 = f2bf(v.z), h3 = f2bf(v.w);
            us4 hv = {h0, h1, h2, h3};
            us4 lv = {f2bf(v.x - bf2f(h0)), f2bf(v.y - bf2f(h1)),
                      f2bf(v.z - bf2f(h2)), f2bf(v.w - bf2f(h3))};
            *(us4*)&Xhi[r][c0 + i * 4] = hv;
            *(us4*)&Xlo[r][c0 + i * 4] = lv;
        }
        ps += __shfl_xor(ps, 1, 64);
        ps += __shfl_xor(ps, 2, 64);
        if ((t & 3) == 0) s_xsq[r] = ps;
    }
    __syncthreads();

    const int w = t >> 6;          // wave 0..7
    const int l = t & 63;          // lane
    const int c = l & 15;
    const int g = l >> 4;
    const int myrow = w * 16 + c;  // this lane's token row within the tile

    // ---- Phase 2: cross S^T = P @ X^T (P single-bf16, X hi/lo) ----
    f32x4 acc[16];
    #pragma unroll
    for (int m = 0; m < 16; ++m) acc[m] = (f32x4){0.f, 0.f, 0.f, 0.f};

    const bf16x8* pfh = (const bf16x8*)PfH;

    #pragma unroll
    for (int kt = 0; kt < 4; ++kt) {
        bf16x8 bh = *(const bf16x8*)&Xhi[myrow][kt * 32 + g * 8];
        bf16x8 bl = *(const bf16x8*)&Xlo[myrow][kt * 32 + g * 8];
        #pragma unroll
        for (int m = 0; m < 16; ++m) {
            bf16x8 ah = pfh[(kt * 16 + m) * 64 + l];
            acc[m] = __builtin_amdgcn_mfma_f32_16x16x32_bf16(ah, bh, acc[m], 0, 0, 0);
            acc[m] = __builtin_amdgcn_mfma_f32_16x16x32_bf16(ah, bl, acc[m], 0, 0, 0);
        }
    }

    // ---- Phase 3: softmax over protos (lane-local 64 + 2 shfl_xor) ----
    const float xq = s_xsq[myrow];
    float mx = -3.4e38f;
    #pragma unroll
    for (int m = 0; m < 16; ++m) {
        #pragma unroll
        for (int r = 0; r < 4; ++r) {
            int proto = m * 16 + g * 4 + r;
            float s2 = fmaxf(xq + s_psq[proto] - 2.f * acc[m][r], 0.f);
            float lg = -sqrtf(s2) * 2.5f;   // 1/T = 1/0.4
            acc[m][r] = lg;
            mx = fmaxf(mx, lg);
        }
    }
    mx = fmaxf(mx, __shfl_xor(mx, 16, 64));
    mx = fmaxf(mx, __shfl_xor(mx, 32, 64));
    float sum = 0.f;
    #pragma unroll
    for (int m = 0; m < 16; ++m) {
        #pragma unroll
        for (int r = 0; r < 4; ++r) {
            float p = __expf(acc[m][r] - mx);
            acc[m][r] = p;
            sum += p;
        }
    }
    sum += __shfl_xor(sum, 16, 64);
    sum += __shfl_xor(sum, 32, 64);
    const float inv = 1.0f / sum;

    // ---- Phase 4: W -> LDS (bf16), then coalesced f32 weight writes ----
    __syncthreads();   // all waves done reading X before overwriting with Wl
    #pragma unroll
    for (int m = 0; m < 16; ++m) {
        us4 wv = {f2bf(acc[m][0] * inv), f2bf(acc[m][1] * inv),
                  f2bf(acc[m][2] * inv), f2bf(acc[m][3] * inv)};
        *(us4*)&Wl[myrow][m * 16 + g * 4] = wv;
    }
    __syncthreads();

    {
        float* wout = weights + base_tok * M_PROTO;
        #pragma unroll
        for (int i = 0; i < 16; ++i) {
            int idx = i * 512 + t;
            int row = idx >> 6;
            int c4  = (idx & 63) * 4;
            us4 wv = *(const us4*)&Wl[row][c4];
            float4 o = {bf2f(wv[0]), bf2f(wv[1]), bf2f(wv[2]), bf2f(wv[3])};
            *(float4*)&wout[row * M_PROTO + c4] = o;
        }
    }

    // ---- Phase 5: blended = W @ P  (K=256; wave w owns output cols w*16..w*16+15) ----
    f32x4 acc2[8];
    #pragma unroll
    for (int m = 0; m < 8; ++m) acc2[m] = (f32x4){0.f, 0.f, 0.f, 0.f};

    const bf16x8* pth = (const bf16x8*)PTfH;
    const bf16x8* ptl = (const bf16x8*)PTfL;

    #pragma unroll
    for (int kt = 0; kt < 8; ++kt) {
        bf16x8 bh = pth[(kt * 8 + w) * 64 + l];
        bf16x8 bl = ptl[(kt * 8 + w) * 64 + l];
        #pragma unroll
        for (int m = 0; m < 8; ++m) {
            bf16x8 aw = *(const bf16x8*)&Wl[m * 16 + c][kt * 32 + g * 8];
            acc2[m] = __builtin_amdgcn_mfma_f32_16x16x32_bf16(aw, bh, acc2[m], 0, 0, 0);
            acc2[m] = __builtin_amdgcn_mfma_f32_16x16x32_bf16(aw, bl, acc2[m], 0, 0, 0);
        }
    }

    float* bout = blended + base_tok * DIM;
    #pragma unroll
    for (int m = 0; m < 8; ++m)
        #pragma unroll
        for (int r = 0; r < 4; ++r) {
            int row = m * 16 + g * 4 + r;
            int d   = w * 16 + c;
            bout[row * DIM + d] = acc2[m][r];
        }
}

extern "C" void kernel_launch(void* const* d_in, const int* in_sizes, int n_in,
                              void* d_out, int out_size, void* d_ws, size_t ws_size,
                              hipStream_t stream) {
    const float* x = (const float*)d_in[0];
    const float* protos = (const float*)d_in[1];

    float* out = (float*)d_out;
    float* blended = out;                               // [N,128]
    float* weights = out + (size_t)N_TOK * DIM;         // [N,256]

    unsigned short* PfH  = (unsigned short*)d_ws;       // 32768 elems each
    unsigned short* PTfH = PfH  + 32768;
    unsigned short* PTfL = PTfH + 32768;
    float*          psq  = (float*)(PTfL + 32768);      // 256 f32

    prep_kernel<<<M_PROTO, DIM, 0, stream>>>(protos, PfH, PTfH, PTfL, psq);
    softsom_main<<<N_TOK / 128, 512, 0, stream>>>(x, PfH, PTfH, PTfL, psq,
                                                  blended, weights);
}